// Round 1
// baseline (304.668 us; speedup 1.0000x reference)
//
#include <hip/hip_runtime.h>
#include <hip/hip_bf16.h>

// DifferentiableXGB: logits = epilogue(x @ W1^T + b1)
//   split[b,n] = sum_d x[b,d]*W1[n,d] + b1[n]          (n = t*4+k, N=400)
//   S[b,t] = sum_k split[b,t,k]
//   logits[b,j] = sum_t fw[t]*S[b,t]*sum_k sigmoid(split[b,t,k])*fc_w[j,k] + fc_b[j]

typedef __bf16 bf16x8 __attribute__((ext_vector_type(8)));
typedef float f32x4 __attribute__((ext_vector_type(4)));

#define B_ROWS 32768
#define D_DIM  1024
#define N_COLS 400      // T*K = 100*4
#define BK     32
#define BM     64
#define NWAVES 5
#define NTPW   5        // N-tiles (16 wide) per wave: 5*5 = 25 = 400/16
#define MT     4        // M-tiles (16 tall) per wave = BM/16
#define THREADS 320
#define A_STRIDE 40     // 32 + 8 pad (shorts) -> 80B row stride, breaks conflicts
#define B_STRIDE 40

__device__ __forceinline__ unsigned short f2bf(float f) {
    unsigned int u = __float_as_uint(f);
    u += 0x7FFFu + ((u >> 16) & 1u);   // RTNE
    return (unsigned short)(u >> 16);
}

__global__ void cvt_w1_kernel(const float* __restrict__ w1,
                              unsigned short* __restrict__ out) {
    int i = (blockIdx.x * 256 + threadIdx.x) * 4;
    const float4 v = *reinterpret_cast<const float4*>(w1 + i);
    ushort4 o;
    o.x = f2bf(v.x); o.y = f2bf(v.y); o.z = f2bf(v.z); o.w = f2bf(v.w);
    *reinterpret_cast<ushort4*>(out + i) = o;
}

template <bool WS_BF16>
__global__ __launch_bounds__(THREADS, 2) void xgb_fused_kernel(
    const float* __restrict__ x,
    const void*  __restrict__ w1_any,   // bf16 (ws) or fp32 (fallback)
    const float* __restrict__ b1,
    const float* __restrict__ fw,
    const float* __restrict__ fcw,      // [2,4]
    const float* __restrict__ fcb,      // [2]
    float* __restrict__ out)            // [B,2]
{
    __shared__ __align__(16) unsigned short Abuf[BM * A_STRIDE];     // 5120 B
    __shared__ __align__(16) unsigned short Bbuf[N_COLS * B_STRIDE]; // 32000 B
    __shared__ float Pbuf[BM * NWAVES * 2];                          // 2560 B

    const int tid  = threadIdx.x;
    const int wave = tid >> 6;
    const int lane = tid & 63;
    const int quad = lane >> 4;
    const int l15  = lane & 15;
    const int row0 = blockIdx.x * BM;

    f32x4 acc[MT][NTPW] = {};

    for (int kc = 0; kc < D_DIM; kc += BK) {
        __syncthreads();   // previous iter's frag reads done before overwrite

        // ---- stage A: 64 rows x 32 cols fp32 -> bf16 (512 float4 slots) ----
        {
            int r = tid >> 3, s = tid & 7;
            const float4 v = *reinterpret_cast<const float4*>(
                x + (row0 + r) * D_DIM + kc + s * 4);
            ushort4 o = { f2bf(v.x), f2bf(v.y), f2bf(v.z), f2bf(v.w) };
            *reinterpret_cast<ushort4*>(&Abuf[r * A_STRIDE + s * 4]) = o;
        }
        if (tid < 512 - THREADS) {
            int i = tid + THREADS;
            int r = i >> 3, s = i & 7;
            const float4 v = *reinterpret_cast<const float4*>(
                x + (row0 + r) * D_DIM + kc + s * 4);
            ushort4 o = { f2bf(v.x), f2bf(v.y), f2bf(v.z), f2bf(v.w) };
            *reinterpret_cast<ushort4*>(&Abuf[r * A_STRIDE + s * 4]) = o;
        }

        // ---- stage B: 400 rows x 32 cols ----
        if (WS_BF16) {
            const unsigned short* w1b = (const unsigned short*)w1_any;
            #pragma unroll
            for (int p = 0; p < 5; ++p) {           // 1600 uint4 slots, exact
                int i = tid + p * THREADS;
                int r = i >> 2, s = i & 3;
                uint4 v = *reinterpret_cast<const uint4*>(
                    w1b + r * D_DIM + kc + s * 8);
                *reinterpret_cast<uint4*>(&Bbuf[r * B_STRIDE + s * 8]) = v;
            }
        } else {
            const float* w1f = (const float*)w1_any;
            #pragma unroll
            for (int p = 0; p < 10; ++p) {          // 3200 float4 slots, exact
                int i = tid + p * THREADS;
                int r = i >> 3, s = i & 7;
                const float4 v = *reinterpret_cast<const float4*>(
                    w1f + r * D_DIM + kc + s * 4);
                ushort4 o = { f2bf(v.x), f2bf(v.y), f2bf(v.z), f2bf(v.w) };
                *reinterpret_cast<ushort4*>(&Bbuf[r * B_STRIDE + s * 4]) = o;
            }
        }
        __syncthreads();

        // ---- frags + MFMA: A[m=l15][k=quad*8+j], B[k=quad*8+j][n=l15] ----
        bf16x8 af[MT];
        #pragma unroll
        for (int m = 0; m < MT; ++m)
            af[m] = *reinterpret_cast<const bf16x8*>(
                &Abuf[(m * 16 + l15) * A_STRIDE + quad * 8]);
        #pragma unroll
        for (int n = 0; n < NTPW; ++n) {
            const int nt = wave * NTPW + n;
            bf16x8 bfr = *reinterpret_cast<const bf16x8*>(
                &Bbuf[(nt * 16 + l15) * B_STRIDE + quad * 8]);
            #pragma unroll
            for (int m = 0; m < MT; ++m)
                acc[m][n] = __builtin_amdgcn_mfma_f32_16x16x32_bf16(
                    af[m], bfr, acc[m][n], 0, 0, 0);
        }
    }

    // ---- epilogue ----
    // C/D layout: col = l15 (within tile), row = quad*4 + reg
    const float fcw0 = fcw[l15 & 3];        // fc_w[0][k], k = col&3
    const float fcw1 = fcw[4 + (l15 & 3)];  // fc_w[1][k]

    float p0[MT][4], p1[MT][4];
    #pragma unroll
    for (int m = 0; m < MT; ++m)
        #pragma unroll
        for (int r = 0; r < 4; ++r) { p0[m][r] = 0.f; p1[m][r] = 0.f; }

    #pragma unroll
    for (int n = 0; n < NTPW; ++n) {
        const int col = (wave * NTPW + n) * 16 + l15;   // global n index
        const float bias = b1[col];
        const float tw   = fw[col >> 2];                // final_weight[t]
        #pragma unroll
        for (int m = 0; m < MT; ++m) {
            #pragma unroll
            for (int r = 0; r < 4; ++r) {
                float split = acc[m][n][r] + bias;
                float s = split;                         // sum over k (lanes^1,^2)
                s += __shfl_xor(s, 1);
                s += __shfl_xor(s, 2);
                float leaf = 1.0f / (1.0f + __expf(-split));
                float val  = tw * leaf * s;
                p0[m][r] += val * fcw0;
                p1[m][r] += val * fcw1;
            }
        }
    }

    // butterfly over 16 cols (lane bits 0-3), then stash per-wave partials
    #pragma unroll
    for (int m = 0; m < MT; ++m) {
        #pragma unroll
        for (int r = 0; r < 4; ++r) {
            float a0 = p0[m][r], a1 = p1[m][r];
            #pragma unroll
            for (int mask = 1; mask < 16; mask <<= 1) {
                a0 += __shfl_xor(a0, mask);
                a1 += __shfl_xor(a1, mask);
            }
            const int row = m * 16 + quad * 4 + r;      // 0..63 within block
            if (l15 == 0) Pbuf[(row * NWAVES + wave) * 2 + 0] = a0;
            if (l15 == 1) Pbuf[(row * NWAVES + wave) * 2 + 1] = a1;
        }
    }
    __syncthreads();

    if (tid < 2 * BM) {
        const int r = tid >> 1, j = tid & 1;
        float s = fcb[j];
        #pragma unroll
        for (int w = 0; w < NWAVES; ++w)
            s += Pbuf[(r * NWAVES + w) * 2 + j];
        out[(row0 + r) * 2 + j] = s;
    }
}

extern "C" void kernel_launch(void* const* d_in, const int* in_sizes, int n_in,
                              void* d_out, int out_size, void* d_ws, size_t ws_size,
                              hipStream_t stream) {
    const float* x   = (const float*)d_in[0];
    const float* W1  = (const float*)d_in[1];
    const float* b1  = (const float*)d_in[2];
    const float* fw  = (const float*)d_in[3];
    const float* fcw = (const float*)d_in[4];
    const float* fcb = (const float*)d_in[5];
    float* out = (float*)d_out;

    const size_t w1_elems = (size_t)N_COLS * D_DIM;   // 409600
    if (ws_size >= w1_elems * sizeof(unsigned short)) {
        unsigned short* w1b = (unsigned short*)d_ws;
        cvt_w1_kernel<<<(int)(w1_elems / 1024), 256, 0, stream>>>(W1, w1b);
        xgb_fused_kernel<true><<<B_ROWS / BM, THREADS, 0, stream>>>(
            x, (const void*)w1b, b1, fw, fcw, fcb, out);
    } else {
        xgb_fused_kernel<false><<<B_ROWS / BM, THREADS, 0, stream>>>(
            x, (const void*)W1, b1, fw, fcw, fcb, out);
    }
}